// Round 7
// baseline (464.387 us; speedup 1.0000x reference)
//
#include <hip/hip_runtime.h>

#define BATCH 262144
#define NH 64     // hidden width
#define NIN 64    // 2*D input width
#define ND 32     // q-dim (output width)
#define TPB 256
#define HALF (BATCH / 2)

// ---------------------------------------------------------------------------
// Prep (re-runs every launch): W2T[j][i] = W2[i][j] (row j = column j of W2).
// ---------------------------------------------------------------------------
__global__ void lnn_prep(const float* __restrict__ W2, float* __restrict__ W2T) {
    int t = blockIdx.x * blockDim.x + threadIdx.x;
    if (t < NH * NH) {
        int i = t >> 6, j = t & 63;          // W2[i][j], row i contiguous
        W2T[j * NH + i] = W2[t];
    }
}

// ---------------------------------------------------------------------------
// TWO samples per thread (t and t+HALF: both X/out streams stay coalesced).
// Each wave-uniform weight row now covers 2x the FMAs -> half the s_load
// stall per FMA, 2x ILP (independent chains). No LDS. Per-sample arithmetic
// order is bit-identical to the round-5/6 passing kernels (absmax 0.0):
// fp32 ascending-i single-accumulator fmaf chains, ONE bias add after.
// Peak live ~150 VGPR (acc0[64]+acc1[64]+temps); 2048 waves = 2 waves/SIMD.
// ---------------------------------------------------------------------------
__global__ __launch_bounds__(TPB) void lnn_main(
        const float* __restrict__ X,
        const float* __restrict__ W1,  const float* __restrict__ b1,
        const float* __restrict__ W2T, const float* __restrict__ b2,
        const float* __restrict__ W3,
        float* __restrict__ out) {
    const int t = blockIdx.x * TPB + threadIdx.x;
    const float* __restrict__ xp0 = X + (size_t)t * NIN;
    const float* __restrict__ xp1 = X + (size_t)(t + HALF) * NIN;

    // ---- phase A: z1 = x @ W1 (per sample: 64 ascending-i single-acc chains)
    float a0[NH], a1[NH];
#pragma unroll
    for (int j = 0; j < NH; ++j) { a0[j] = 0.f; a1[j] = 0.f; }

#pragma unroll 1
    for (int ig = 0; ig < NIN / 4; ++ig) {
        const float4 xv0 = reinterpret_cast<const float4*>(xp0)[ig];
        const float4 xv1 = reinterpret_cast<const float4*>(xp1)[ig];
        const float xs0[4] = {xv0.x, xv0.y, xv0.z, xv0.w};
        const float xs1[4] = {xv1.x, xv1.y, xv1.z, xv1.w};
#pragma unroll
        for (int ii = 0; ii < 4; ++ii) {
            const float* __restrict__ wr = W1 + (ig * 4 + ii) * NH;  // uniform
#pragma unroll
            for (int j = 0; j < NH; ++j) {
                a0[j] = fmaf(xs0[ii], wr[j], a0[j]);
                a1[j] = fmaf(xs1[ii], wr[j], a1[j]);
            }
        }
    }

    // z1 = acc + b1 (ONE rounded add AFTER the chain); mask; relu in place.
    unsigned r1lo0 = 0u, r1hi0 = 0u, r1lo1 = 0u, r1hi1 = 0u;
#pragma unroll
    for (int j = 0; j < NH; ++j) {
        const float bj = b1[j];
        const float z0 = a0[j] + bj;
        const float z1 = a1[j] + bj;
        if (j < 32) {
            if (z0 > 0.f) r1lo0 |= (1u << j);
            if (z1 > 0.f) r1lo1 |= (1u << j);
        } else {
            if (z0 > 0.f) r1hi0 |= (1u << (j - 32));
            if (z1 > 0.f) r1hi1 |= (1u << (j - 32));
        }
        a0[j] = fmaxf(z0, 0.f);
        a1[j] = fmaxf(z1, 0.f);
    }

    // ---- phase B1: z2_j = (h . W2T[j][:]) + b2_j; sign bits only.
    // 4 j-rows per outer iteration; per row one single-scalar ascending-i
    // chain per sample (8 independent chains in flight).
    unsigned r2lo0 = 0u, r2hi0 = 0u, r2lo1 = 0u, r2hi1 = 0u;
#pragma unroll 1
    for (int jg = 0; jg < NH / 4; ++jg) {
        const float* __restrict__ q0 = W2T + (jg * 4 + 0) * NH;  // uniform rows
        const float* __restrict__ q1 = W2T + (jg * 4 + 1) * NH;
        const float* __restrict__ q2 = W2T + (jg * 4 + 2) * NH;
        const float* __restrict__ q3 = W2T + (jg * 4 + 3) * NH;
        float p00 = 0.f, p01 = 0.f, p02 = 0.f, p03 = 0.f;
        float p10 = 0.f, p11 = 0.f, p12 = 0.f, p13 = 0.f;
#pragma unroll
        for (int i = 0; i < NH; ++i) {
            const float h0 = a0[i], h1 = a1[i];
            p00 = fmaf(h0, q0[i], p00);  p10 = fmaf(h1, q0[i], p10);
            p01 = fmaf(h0, q1[i], p01);  p11 = fmaf(h1, q1[i], p11);
            p02 = fmaf(h0, q2[i], p02);  p12 = fmaf(h1, q2[i], p12);
            p03 = fmaf(h0, q3[i], p03);  p13 = fmaf(h1, q3[i], p13);
        }
        const int j0 = jg * 4;
        unsigned bits0 = 0u, bits1 = 0u;
        if (p00 + b2[j0 + 0] > 0.f) bits0 |= 1u;
        if (p01 + b2[j0 + 1] > 0.f) bits0 |= 2u;
        if (p02 + b2[j0 + 2] > 0.f) bits0 |= 4u;
        if (p03 + b2[j0 + 3] > 0.f) bits0 |= 8u;
        if (p10 + b2[j0 + 0] > 0.f) bits1 |= 1u;
        if (p11 + b2[j0 + 1] > 0.f) bits1 |= 2u;
        if (p12 + b2[j0 + 2] > 0.f) bits1 |= 4u;
        if (p13 + b2[j0 + 3] > 0.f) bits1 |= 8u;
        if (j0 < 32) { r2lo0 |= bits0 << j0;        r2lo1 |= bits1 << j0; }
        else         { r2hi0 |= bits0 << (j0 - 32); r2hi1 |= bits1 << (j0 - 32); }
    }
    // h (a0/a1) dead after B1 -> reuse as t-vectors.

    // ---- phase B2 (values): t_j = sum_{j2 in r2} w3_j2 * W2T[j2][j] ----
#pragma unroll
    for (int j = 0; j < NH; ++j) { a0[j] = 0.f; a1[j] = 0.f; }

#pragma unroll 1
    for (int j2 = 0; j2 < NH; ++j2) {
        const bool m0 = (j2 < 32) ? ((r2lo0 >> j2) & 1u) : ((r2hi0 >> (j2 - 32)) & 1u);
        const bool m1 = (j2 < 32) ? ((r2lo1 >> j2) & 1u) : ((r2hi1 >> (j2 - 32)) & 1u);
        const float w3v = W3[j2];
        const float ms0 = m0 ? w3v : 0.f;
        const float ms1 = m1 ? w3v : 0.f;
        const float* __restrict__ wr = W2T + j2 * NH;            // uniform row
#pragma unroll
        for (int j = 0; j < NH; ++j) {
            a0[j] = fmaf(ms0, wr[j], a0[j]);
            a1[j] = fmaf(ms1, wr[j], a1[j]);
        }
    }

    // u = r1 .* t (in place)
#pragma unroll
    for (int j = 0; j < NH; ++j) {
        const bool m0 = (j < 32) ? ((r1lo0 >> j) & 1u) : ((r1hi0 >> (j - 32)) & 1u);
        const bool m1 = (j < 32) ? ((r1lo1 >> j) & 1u) : ((r1hi1 >> (j - 32)) & 1u);
        a0[j] = m0 ? a0[j] : 0.f;
        a1[j] = m1 ? a1[j] : 0.f;
    }

    // ---- phase C (values): out_k = -(W1 row k) . u; 4 k-rows x 2 samples.
    float* __restrict__ op0 = out + (size_t)t * ND;
    float* __restrict__ op1 = out + (size_t)(t + HALF) * ND;
#pragma unroll 1
    for (int kq = 0; kq < ND / 4; ++kq) {
        const float* __restrict__ w0 = W1 + (kq * 4 + 0) * NH;   // uniform rows
        const float* __restrict__ w1 = W1 + (kq * 4 + 1) * NH;
        const float* __restrict__ w2 = W1 + (kq * 4 + 2) * NH;
        const float* __restrict__ w3r = W1 + (kq * 4 + 3) * NH;
        float c00 = 0.f, c01 = 0.f, c02 = 0.f, c03 = 0.f;
        float c10 = 0.f, c11 = 0.f, c12 = 0.f, c13 = 0.f;
#pragma unroll
        for (int i = 0; i < NH; ++i) {
            const float u0 = a0[i], u1 = a1[i];
            c00 = fmaf(w0[i],  u0, c00);  c10 = fmaf(w0[i],  u1, c10);
            c01 = fmaf(w1[i],  u0, c01);  c11 = fmaf(w1[i],  u1, c11);
            c02 = fmaf(w2[i],  u0, c02);  c12 = fmaf(w2[i],  u1, c12);
            c03 = fmaf(w3r[i], u0, c03);  c13 = fmaf(w3r[i], u1, c13);
        }
        float4 ov0, ov1;
        ov0.x = -c00; ov0.y = -c01; ov0.z = -c02; ov0.w = -c03;
        ov1.x = -c10; ov1.y = -c11; ov1.z = -c12; ov1.w = -c13;
        reinterpret_cast<float4*>(op0)[kq] = ov0;
        reinterpret_cast<float4*>(op1)[kq] = ov1;
    }
}

extern "C" void kernel_launch(void* const* d_in, const int* in_sizes, int n_in,
                              void* d_out, int out_size, void* d_ws, size_t ws_size,
                              hipStream_t stream) {
    const float* X  = (const float*)d_in[0];
    const float* W1 = (const float*)d_in[1];
    const float* b1 = (const float*)d_in[2];
    const float* W2 = (const float*)d_in[3];
    const float* b2 = (const float*)d_in[4];
    const float* W3 = (const float*)d_in[5];
    // d_in[6] = b3: does not affect gradients.
    float* out = (float*)d_out;

    float* W2T = (float*)d_ws;            // 16384 B

    lnn_prep<<<16, 256, 0, stream>>>(W2, W2T);
    lnn_main<<<HALF / TPB, TPB, 0, stream>>>(X, W1, b1, W2T, b2, W3, out);
}

// Round 8
// 284.719 us; speedup vs baseline: 1.6310x; 1.6310x over previous
//
#include <hip/hip_runtime.h>
#include <hip/hip_bf16.h>

#define BATCH     262144
#define TPB       256
#define GRID_MAIN 2048          // BATCH / 128 samples-per-block
#define FLAG_CAP  24576
#define EPS1      2.0e-4f
#define EPS2      4.0e-4f

typedef __attribute__((ext_vector_type(8))) short bf16x8;
typedef __attribute__((ext_vector_type(4))) float f32x4;

union FragU { unsigned int u[4]; bf16x8 v; int4 i4; };

__device__ __forceinline__ unsigned short f2bf(float x) {
    __hip_bfloat16 h = __float2bfloat16(x);     // RNE
    unsigned short u; __builtin_memcpy(&u, &h, 2); return u;
}
__device__ __forceinline__ float bf2f(unsigned short u) {
    unsigned int w = ((unsigned int)u) << 16;
    float f; __builtin_memcpy(&f, &w, 4); return f;
}

// ---------------------------------------------------------------------------
// Prep: build all MFMA A-fragment arrays in frag-major layout, split hi/lo
// bf16; plus fp32 transposes for the repair kernel; zero the flag counter.
// Frag element map (v_mfma_f32_16x16x32_bf16): lane l: A row = l&15,
// k = (l>>4)*8 + e (e=0..7, packed 2 bf16 per u32, even in low half).
// ---------------------------------------------------------------------------
__global__ void lnn_prep(const float* __restrict__ W1, const float* __restrict__ b1,
                         const float* __restrict__ W2, const float* __restrict__ b2,
                         const float* __restrict__ W3,
                         unsigned int* __restrict__ W1AH, unsigned int* __restrict__ W1AL,
                         unsigned int* __restrict__ W2AH, unsigned int* __restrict__ W2AL,
                         unsigned int* __restrict__ VA,   unsigned int* __restrict__ W4A,
                         float* __restrict__ B1A, float* __restrict__ B2A,
                         float* __restrict__ W2T, float* __restrict__ W1T32,
                         unsigned int* __restrict__ cnt) {
    const int g = blockIdx.x * blockDim.x + threadIdx.x;   // 16384 threads
    if (g == 0) *cnt = 0u;

    for (int t = g; t < 8 * 64 * 4; t += 16384) {          // [idx][lane][r]
        const int idx = t >> 8, lane = (t >> 2) & 63, r = t & 3;
        const int jt = idx >> 1, kc = idx & 1;
        const int row = lane & 15;
        const int k0 = kc * 32 + (lane >> 4) * 8 + 2 * r;  // even element
        // G1 A = W1^T: A[j, i] = W1[i*64 + j]
        {
            const int j = jt * 16 + row;
            const float v0 = W1[(k0 + 0) * 64 + j], v1 = W1[(k0 + 1) * 64 + j];
            const unsigned short h0 = f2bf(v0), h1 = f2bf(v1);
            const unsigned short l0 = f2bf(v0 - bf2f(h0)), l1 = f2bf(v1 - bf2f(h1));
            W1AH[t] = (unsigned)h0 | ((unsigned)h1 << 16);
            W1AL[t] = (unsigned)l0 | ((unsigned)l1 << 16);
        }
        // G2 A = W2^T: A[j2, i] = W2[i*64 + j2]
        {
            const int j2 = jt * 16 + row;
            const float v0 = W2[(k0 + 0) * 64 + j2], v1 = W2[(k0 + 1) * 64 + j2];
            const unsigned short h0 = f2bf(v0), h1 = f2bf(v1);
            const unsigned short l0 = f2bf(v0 - bf2f(h0)), l1 = f2bf(v1 - bf2f(h1));
            W2AH[t] = (unsigned)h0 | ((unsigned)h1 << 16);
            W2AL[t] = (unsigned)l0 | ((unsigned)l1 << 16);
        }
        // G3 A = V^T: A[j, j2] = w3[j2] * W2[j*64 + j2]  (single bf16)
        {
            const int j = jt * 16 + row;
            const float v0 = W3[k0 + 0] * W2[j * 64 + (k0 + 0)];
            const float v1 = W3[k0 + 1] * W2[j * 64 + (k0 + 1)];
            VA[t] = (unsigned)f2bf(v0) | ((unsigned)f2bf(v1) << 16);
        }
        // G4 A = -W1 rows k<32: A[k, i] = -W1[k*64 + i] (single bf16; idx<4)
        if (idx < 4) {
            const int mt = idx >> 1;
            const int k = mt * 16 + row;
            const float v0 = -W1[k * 64 + (k0 + 0)], v1 = -W1[k * 64 + (k0 + 1)];
            W4A[t] = (unsigned)f2bf(v0) | ((unsigned)f2bf(v1) << 16);
        }
    }
    for (int t = g; t < 4 * 64 * 4; t += 16384) {          // bias frags (C layout)
        const int jt = t >> 8, lane = (t >> 2) & 63, r = t & 3;
        const int j = jt * 16 + (lane >> 4) * 4 + r;
        B1A[t] = b1[j];
        B2A[t] = b2[j];
    }
    for (int t = g; t < 64 * 64; t += 16384) {             // repair: W2T[j2][j]
        const int i = t >> 6, j = t & 63;
        W2T[j * 64 + i] = W2[i * 64 + j];
    }
    for (int t = g; t < 64 * 32; t += 16384) {             // repair: W1T32[i][k]
        const int i = t >> 5, k = t & 31;
        W1T32[i * 32 + k] = W1[k * 64 + i];
    }
}

// ---------------------------------------------------------------------------
// Main: transposed MFMA pipeline. Block = 4 waves x 32 samples. Per wave:
//   G1: Z1^T[64j,32s] = W1^T x X^T   (split bf16, 3 products)  -> masks m1, h
//   G2: Z2^T = W2^T x H^T            (split bf16, 3 products)  -> M2 (0/1)
//   G3: T^T  = V^T  x M2^T           (bf16)                    -> U = m1.*T
//   G4: OUT^T= (-W1k) x U            (bf16)                    -> store
// Cells with |z| < EPS flag the sample for exact repair.
// ---------------------------------------------------------------------------
__global__ __launch_bounds__(TPB) void lnn_mfma(
        const float* __restrict__ X,
        const unsigned int* __restrict__ W1AH, const unsigned int* __restrict__ W1AL,
        const unsigned int* __restrict__ W2AH, const unsigned int* __restrict__ W2AL,
        const unsigned int* __restrict__ VA,   const unsigned int* __restrict__ W4A,
        const float* __restrict__ B1A, const float* __restrict__ B2A,
        unsigned int* __restrict__ cnt, unsigned int* __restrict__ flagIdx,
        float* __restrict__ out) {
    __shared__ unsigned int  HB[4][64][33];   // packed (h_hi | h_lo<<16)
    __shared__ unsigned short MU[4][64][33];  // M2 then reused as U (bf16)

    const int tid = threadIdx.x;
    const int w  = tid >> 6;
    const int l  = tid & 63;
    const int lr = l & 15;                    // A-row / B-col / C-col in tile
    const int lg = l >> 4;                    // k-group / C-row group
    const int s0 = blockIdx.x * 128 + w * 32;

    const f32x4 zz = {0.f, 0.f, 0.f, 0.f};
    f32x4 acc[4][2];

    // ================= G1 =================
#pragma unroll
    for (int jt = 0; jt < 4; ++jt)
#pragma unroll
        for (int nt = 0; nt < 2; ++nt) acc[jt][nt] = zz;

#pragma unroll
    for (int kc = 0; kc < 2; ++kc) {
        FragU bh[2], bl[2];
#pragma unroll
        for (int nt = 0; nt < 2; ++nt) {
            const float* xp = X + (size_t)(s0 + nt * 16 + lr) * 64 + kc * 32 + lg * 8;
            const float4 x0 = reinterpret_cast<const float4*>(xp)[0];
            const float4 x1 = reinterpret_cast<const float4*>(xp)[1];
            const float xs[8] = {x0.x, x0.y, x0.z, x0.w, x1.x, x1.y, x1.z, x1.w};
#pragma unroll
            for (int r = 0; r < 4; ++r) {
                const unsigned short h0 = f2bf(xs[2 * r]),     h1 = f2bf(xs[2 * r + 1]);
                const unsigned short q0 = f2bf(xs[2 * r] - bf2f(h0));
                const unsigned short q1 = f2bf(xs[2 * r + 1] - bf2f(h1));
                bh[nt].u[r] = (unsigned)h0 | ((unsigned)h1 << 16);
                bl[nt].u[r] = (unsigned)q0 | ((unsigned)q1 << 16);
            }
        }
#pragma unroll
        for (int jt = 0; jt < 4; ++jt) {
            FragU ah, al;
            ah.i4 = reinterpret_cast<const int4*>(W1AH)[(jt * 2 + kc) * 64 + l];
            al.i4 = reinterpret_cast<const int4*>(W1AL)[(jt * 2 + kc) * 64 + l];
#pragma unroll
            for (int nt = 0; nt < 2; ++nt) {
                acc[jt][nt] = __builtin_amdgcn_mfma_f32_16x16x32_bf16(al.v, bh[nt].v, acc[jt][nt], 0, 0, 0);
                acc[jt][nt] = __builtin_amdgcn_mfma_f32_16x16x32_bf16(ah.v, bl[nt].v, acc[jt][nt], 0, 0, 0);
                acc[jt][nt] = __builtin_amdgcn_mfma_f32_16x16x32_bf16(ah.v, bh[nt].v, acc[jt][nt], 0, 0, 0);
            }
        }
    }

    unsigned int m1 = 0u;
#pragma unroll
    for (int jt = 0; jt < 4; ++jt) {
        const float4 bv = reinterpret_cast<const float4*>(B1A)[jt * 64 + l];
        const float bb[4] = {bv.x, bv.y, bv.z, bv.w};
#pragma unroll
        for (int nt = 0; nt < 2; ++nt) {
            const int sc = nt * 16 + lr;
#pragma unroll
            for (int r = 0; r < 4; ++r) {
                const float z = acc[jt][nt][r] + bb[r];
                if (z > 0.f) m1 |= 1u << (jt * 8 + nt * 4 + r);
                if (__builtin_fabsf(z) < EPS1) {
                    const unsigned int pos = atomicAdd(cnt, 1u);
                    if (pos < FLAG_CAP) flagIdx[pos] = (unsigned int)(s0 + sc);
                }
                const float h = fmaxf(z, 0.f);
                const unsigned short hh = f2bf(h);
                const unsigned short hl = f2bf(h - bf2f(hh));
                HB[w][jt * 16 + lg * 4 + r][sc] = (unsigned)hh | ((unsigned)hl << 16);
            }
        }
    }

    // ================= G2 =================
#pragma unroll
    for (int jt = 0; jt < 4; ++jt)
#pragma unroll
        for (int nt = 0; nt < 2; ++nt) acc[jt][nt] = zz;

#pragma unroll
    for (int kc = 0; kc < 2; ++kc) {
        FragU bh[2], bl[2];
#pragma unroll
        for (int nt = 0; nt < 2; ++nt) {
            const int sc = nt * 16 + lr;
#pragma unroll
            for (int r = 0; r < 4; ++r) {
                const int i0 = kc * 32 + lg * 8 + 2 * r;
                const unsigned int ue = HB[w][i0][sc];
                const unsigned int uo = HB[w][i0 + 1][sc];
                bh[nt].u[r] = (ue & 0xFFFFu) | (uo << 16);
                bl[nt].u[r] = (ue >> 16) | (uo & 0xFFFF0000u);
            }
        }
#pragma unroll
        for (int jt = 0; jt < 4; ++jt) {
            FragU ah, al;
            ah.i4 = reinterpret_cast<const int4*>(W2AH)[(jt * 2 + kc) * 64 + l];
            al.i4 = reinterpret_cast<const int4*>(W2AL)[(jt * 2 + kc) * 64 + l];
#pragma unroll
            for (int nt = 0; nt < 2; ++nt) {
                acc[jt][nt] = __builtin_amdgcn_mfma_f32_16x16x32_bf16(al.v, bh[nt].v, acc[jt][nt], 0, 0, 0);
                acc[jt][nt] = __builtin_amdgcn_mfma_f32_16x16x32_bf16(ah.v, bl[nt].v, acc[jt][nt], 0, 0, 0);
                acc[jt][nt] = __builtin_amdgcn_mfma_f32_16x16x32_bf16(ah.v, bh[nt].v, acc[jt][nt], 0, 0, 0);
            }
        }
    }

#pragma unroll
    for (int jt = 0; jt < 4; ++jt) {
        const float4 bv = reinterpret_cast<const float4*>(B2A)[jt * 64 + l];
        const float bb[4] = {bv.x, bv.y, bv.z, bv.w};
#pragma unroll
        for (int nt = 0; nt < 2; ++nt) {
            const int sc = nt * 16 + lr;
#pragma unroll
            for (int r = 0; r < 4; ++r) {
                const float z = acc[jt][nt][r] + bb[r];
                MU[w][jt * 16 + lg * 4 + r][sc] = (z > 0.f) ? (unsigned short)0x3F80u
                                                            : (unsigned short)0u;
                if (__builtin_fabsf(z) < EPS2) {
                    const unsigned int pos = atomicAdd(cnt, 1u);
                    if (pos < FLAG_CAP) flagIdx[pos] = (unsigned int)(s0 + sc);
                }
            }
        }
    }

    // ================= G3 =================
#pragma unroll
    for (int jt = 0; jt < 4; ++jt)
#pragma unroll
        for (int nt = 0; nt < 2; ++nt) acc[jt][nt] = zz;

#pragma unroll
    for (int kc = 0; kc < 2; ++kc) {
        FragU bm[2];
#pragma unroll
        for (int nt = 0; nt < 2; ++nt) {
            const int sc = nt * 16 + lr;
#pragma unroll
            for (int r = 0; r < 4; ++r) {
                const int i0 = kc * 32 + lg * 8 + 2 * r;
                const unsigned int ue = MU[w][i0][sc];
                const unsigned int uo = MU[w][i0 + 1][sc];
                bm[nt].u[r] = ue | (uo << 16);
            }
        }
#pragma unroll
        for (int jt = 0; jt < 4; ++jt) {
            FragU av;
            av.i4 = reinterpret_cast<const int4*>(VA)[(jt * 2 + kc) * 64 + l];
#pragma unroll
            for (int nt = 0; nt < 2; ++nt)
                acc[jt][nt] = __builtin_amdgcn_mfma_f32_16x16x32_bf16(av.v, bm[nt].v, acc[jt][nt], 0, 0, 0);
        }
    }
    // U = m1 .* T  (same C-layout cell-to-lane mapping as G1 -> m1 in register)
#pragma unroll
    for (int jt = 0; jt < 4; ++jt)
#pragma unroll
        for (int nt = 0; nt < 2; ++nt) {
            const int sc = nt * 16 + lr;
#pragma unroll
            for (int r = 0; r < 4; ++r) {
                const float uv = ((m1 >> (jt * 8 + nt * 4 + r)) & 1u) ? acc[jt][nt][r] : 0.f;
                MU[w][jt * 16 + lg * 4 + r][sc] = f2bf(uv);
            }
        }

    // ================= G4 =================
    f32x4 acc4[2][2];
#pragma unroll
    for (int mt = 0; mt < 2; ++mt)
#pragma unroll
        for (int nt = 0; nt < 2; ++nt) acc4[mt][nt] = zz;

#pragma unroll
    for (int kc = 0; kc < 2; ++kc) {
        FragU bu[2];
#pragma unroll
        for (int nt = 0; nt < 2; ++nt) {
            const int sc = nt * 16 + lr;
#pragma unroll
            for (int r = 0; r < 4; ++r) {
                const int i0 = kc * 32 + lg * 8 + 2 * r;
                const unsigned int ue = MU[w][i0][sc];
                const unsigned int uo = MU[w][i0 + 1][sc];
                bu[nt].u[r] = ue | (uo << 16);
            }
        }
#pragma unroll
        for (int mt = 0; mt < 2; ++mt) {
            FragU a4;
            a4.i4 = reinterpret_cast<const int4*>(W4A)[(mt * 2 + kc) * 64 + l];
#pragma unroll
            for (int nt = 0; nt < 2; ++nt)
                acc4[mt][nt] = __builtin_amdgcn_mfma_f32_16x16x32_bf16(a4.v, bu[nt].v, acc4[mt][nt], 0, 0, 0);
        }
    }
#pragma unroll
    for (int mt = 0; mt < 2; ++mt)
#pragma unroll
        for (int nt = 0; nt < 2; ++nt)
#pragma unroll
            for (int r = 0; r < 4; ++r)
                out[(size_t)(s0 + nt * 16 + lr) * 32 + mt * 16 + lg * 4 + r] = acc4[mt][nt][r];
}

// ---------------------------------------------------------------------------
// Repair: one wave per flagged sample; exact fp32 ascending-i single-acc
// chains (bit-identical to sgemm reference), masks via 64-bit ballot.
// ---------------------------------------------------------------------------
__global__ __launch_bounds__(64) void lnn_repair(
        const float* __restrict__ X,
        const float* __restrict__ W1, const float* __restrict__ b1,
        const float* __restrict__ W2, const float* __restrict__ b2,
        const float* __restrict__ W3, const float* __restrict__ W2T,
        const float* __restrict__ W1T32,
        const unsigned int* __restrict__ cnt, const unsigned int* __restrict__ flagIdx,
        float* __restrict__ out) {
    const int l = threadIdx.x;
    int n = (int)*cnt;
    if (n > FLAG_CAP) n = FLAG_CAP;

    for (int idx = blockIdx.x; idx < n; idx += gridDim.x) {
        const int s = (int)flagIdx[idx];
        const float xv = X[(size_t)s * 64 + l];

        float z1 = 0.f;
        for (int i = 0; i < 64; ++i)
            z1 = fmaf(__shfl(xv, i), W1[i * 64 + l], z1);   // ascending, single acc
        z1 += b1[l];                                         // one rounded add
        const unsigned long long m1 = __ballot(z1 > 0.f);
        const float h = fmaxf(z1, 0.f);

        float z2 = 0.f;
        for (int i = 0; i < 64; ++i)
            z2 = fmaf(__shfl(h, i), W2[i * 64 + l], z2);
        z2 += b2[l];
        const unsigned long long m2 = __ballot(z2 > 0.f);

        float t = 0.f;
        for (int j2 = 0; j2 < 64; ++j2)
            if ((m2 >> j2) & 1ull) t = fmaf(W3[j2], W2T[j2 * 64 + l], t);
        const float u = ((m1 >> l) & 1ull) ? t : 0.f;

        float o = 0.f;
        for (int i = 0; i < 64; ++i)
            o = fmaf(__shfl(u, i), (l < 32) ? W1T32[i * 32 + l] : 0.f, o);
        if (l < 32) out[(size_t)s * 32 + l] = -o;
    }
}

extern "C" void kernel_launch(void* const* d_in, const int* in_sizes, int n_in,
                              void* d_out, int out_size, void* d_ws, size_t ws_size,
                              hipStream_t stream) {
    const float* X  = (const float*)d_in[0];
    const float* W1 = (const float*)d_in[1];
    const float* b1 = (const float*)d_in[2];
    const float* W2 = (const float*)d_in[3];
    const float* b2 = (const float*)d_in[4];
    const float* W3 = (const float*)d_in[5];
    // d_in[6] = b3: does not affect gradients.
    float* out = (float*)d_out;

    char* ws = (char*)d_ws;
    unsigned int* W1AH = (unsigned int*)(ws + 0);        //  8 KB
    unsigned int* W1AL = (unsigned int*)(ws + 8192);     //  8 KB
    unsigned int* W2AH = (unsigned int*)(ws + 16384);    //  8 KB
    unsigned int* W2AL = (unsigned int*)(ws + 24576);    //  8 KB
    unsigned int* VAp  = (unsigned int*)(ws + 32768);    //  8 KB
    unsigned int* W4Ap = (unsigned int*)(ws + 40960);    //  4 KB
    float*        B1A  = (float*)(ws + 45056);           //  4 KB
    float*        B2A  = (float*)(ws + 49152);           //  4 KB
    float*        W2T  = (float*)(ws + 53248);           // 16 KB
    float*        W1T32= (float*)(ws + 69632);           //  8 KB
    unsigned int* CNT  = (unsigned int*)(ws + 77824);    // 16 B
    unsigned int* FIDX = (unsigned int*)(ws + 77840);    // 96 KB

    lnn_prep<<<64, 256, 0, stream>>>(W1, b1, W2, b2, W3,
                                     W1AH, W1AL, W2AH, W2AL, VAp, W4Ap,
                                     B1A, B2A, W2T, W1T32, CNT);
    lnn_mfma<<<GRID_MAIN, TPB, 0, stream>>>(X, W1AH, W1AL, W2AH, W2AL, VAp, W4Ap,
                                            B1A, B2A, CNT, FIDX, out);
    lnn_repair<<<2048, 64, 0, stream>>>(X, W1, b1, W2, b2, W3, W2T, W1T32,
                                        CNT, FIDX, out);
}